// Round 1
// baseline (2837.806 us; speedup 1.0000x reference)
//
#include <hip/hip_runtime.h>
#include <math.h>

// Problem constants (fixed by setup_inputs)
constexpr int B_ = 4, S_ = 8192, D_ = 1024, H_ = 1024, O_ = 1024;
// Tile config
constexpr int TS = 64, TH = 64, TK = 16, LDP = 68; // LDP: padded row (mult of 4 for b128 align)

__device__ __forceinline__ float softplusf(float x) {
    if (x > 20.f) return x;
    if (x < -20.f) return expf(x);
    return log1pf(expf(x));
}

// z = x @ w_in^T fused with elementwise chain and reduction over s.
// Math: h_last[b,h] = exp(-sp(diff_{S-1})) * (0.5 + sum_s exp(diff_s + log_g(hgate_s)))
//   where diff = sp(-f) - sp(-i), log_g(x) = x>=0 ? log(x+0.5) : -sp(-x)
__global__ __launch_bounds__(256) void fused_gemm_reduce(
    const float* __restrict__ x, const float* __restrict__ win,
    float* __restrict__ acc_ws, float* __restrict__ F_ws)
{
    __shared__ __align__(16) float As[TK][LDP];
    __shared__ __align__(16) float Wf[TK][LDP];
    __shared__ __align__(16) float Wi[TK][LDP];
    __shared__ __align__(16) float Wh[TK][LDP];
    __shared__ float colsum[TH];

    const int b  = blockIdx.z;
    const int s0 = blockIdx.x * TS;
    const int h0 = blockIdx.y * TH;
    const int tid = threadIdx.x;
    const int tx = tid & 15;   // column group (4 cols each)
    const int ty = tid >> 4;   // row group (4 rows each)

    float accf[4][4] = {};
    float acci[4][4] = {};
    float acch[4][4] = {};

    // loader mapping: each thread loads one float4 per tile per K-chunk
    const int lrow = tid >> 2;        // 0..63
    const int lk4  = (tid & 3) << 2;  // 0,4,8,12

    const float* xp  = x   + ((size_t)b * S_ + (s0 + lrow)) * D_ + lk4;
    const float* wfp = win + (size_t)(h0 + lrow) * D_ + lk4;
    const float* wip = wfp + (size_t)H_ * D_;
    const float* whp = wip + (size_t)H_ * D_;

    for (int k0 = 0; k0 < D_; k0 += TK) {
        float4 va = *(const float4*)(xp  + k0);
        float4 vf = *(const float4*)(wfp + k0);
        float4 vi = *(const float4*)(wip + k0);
        float4 vh = *(const float4*)(whp + k0);
        __syncthreads();
        // transpose-scatter into [k][row] layout so compute reads are b128
        As[lk4+0][lrow]=va.x; As[lk4+1][lrow]=va.y; As[lk4+2][lrow]=va.z; As[lk4+3][lrow]=va.w;
        Wf[lk4+0][lrow]=vf.x; Wf[lk4+1][lrow]=vf.y; Wf[lk4+2][lrow]=vf.z; Wf[lk4+3][lrow]=vf.w;
        Wi[lk4+0][lrow]=vi.x; Wi[lk4+1][lrow]=vi.y; Wi[lk4+2][lrow]=vi.z; Wi[lk4+3][lrow]=vi.w;
        Wh[lk4+0][lrow]=vh.x; Wh[lk4+1][lrow]=vh.y; Wh[lk4+2][lrow]=vh.z; Wh[lk4+3][lrow]=vh.w;
        __syncthreads();
        #pragma unroll
        for (int k = 0; k < TK; ++k) {
            float4 a4 = *(const float4*)&As[k][ty << 2];
            float4 f4 = *(const float4*)&Wf[k][tx << 2];
            float4 i4 = *(const float4*)&Wi[k][tx << 2];
            float4 h4 = *(const float4*)&Wh[k][tx << 2];
            float a[4]  = {a4.x, a4.y, a4.z, a4.w};
            float wf[4] = {f4.x, f4.y, f4.z, f4.w};
            float wi[4] = {i4.x, i4.y, i4.z, i4.w};
            float wh[4] = {h4.x, h4.y, h4.z, h4.w};
            #pragma unroll
            for (int r = 0; r < 4; ++r) {
                #pragma unroll
                for (int c = 0; c < 4; ++c) {
                    accf[r][c] = fmaf(a[r], wf[c], accf[r][c]);
                    acci[r][c] = fmaf(a[r], wi[c], acci[r][c]);
                    acch[r][c] = fmaf(a[r], wh[c], acch[r][c]);
                }
            }
        }
    }

    // Elementwise chain + per-column partials
    const bool last_s = (s0 + TS == S_);
    float cval[4] = {0.f, 0.f, 0.f, 0.f};
    #pragma unroll
    for (int c = 0; c < 4; ++c) {
        #pragma unroll
        for (int r = 0; r < 4; ++r) {
            float f = accf[r][c], i = acci[r][c], h = acch[r][c];
            float d  = softplusf(-f) - softplusf(-i);
            float lg = (h >= 0.f) ? logf(h + 0.5f) : -softplusf(-h);
            cval[c] += expf(d + lg);
            if (last_s && ty == 15 && r == 3) {
                // this thread owns global row S-1 for its 4 columns
                F_ws[(size_t)b * H_ + h0 + (tx << 2) + c] = expf(-softplusf(d));
            }
        }
    }
    if (tid < TH) colsum[tid] = 0.f;
    __syncthreads();
    #pragma unroll
    for (int c = 0; c < 4; ++c)
        atomicAdd(&colsum[(tx << 2) + c], cval[c]);
    __syncthreads();
    if (tid < TH)
        atomicAdd(&acc_ws[(size_t)b * H_ + h0 + tid], colsum[tid]);
}

// out[b,o] = b_out[o] + sum_h w_out[o,h] * F[b,h]*(0.5 + acc[b,h])
__global__ __launch_bounds__(256) void out_gemv(
    const float* __restrict__ wout, const float* __restrict__ bout,
    const float* __restrict__ acc_ws, const float* __restrict__ F_ws,
    float* __restrict__ out)
{
    const int lane = threadIdx.x & 63;
    const int o = blockIdx.x * 4 + (threadIdx.x >> 6);
    float s[B_] = {};
    for (int h = lane; h < H_; h += 64) {
        float w = wout[(size_t)o * H_ + h];
        #pragma unroll
        for (int b = 0; b < B_; ++b) {
            float hv = F_ws[b * H_ + h] * (0.5f + acc_ws[b * H_ + h]);
            s[b] = fmaf(w, hv, s[b]);
        }
    }
    #pragma unroll
    for (int b = 0; b < B_; ++b) {
        #pragma unroll
        for (int off = 32; off > 0; off >>= 1)
            s[b] += __shfl_down(s[b], off, 64);
    }
    if (lane == 0) {
        float bo = bout[o];
        #pragma unroll
        for (int b = 0; b < B_; ++b)
            out[(size_t)b * O_ + o] = s[b] + bo;
    }
}

extern "C" void kernel_launch(void* const* d_in, const int* in_sizes, int n_in,
                              void* d_out, int out_size, void* d_ws, size_t ws_size,
                              hipStream_t stream) {
    const float* x    = (const float*)d_in[0];
    const float* w_in = (const float*)d_in[1];
    const float* wout = (const float*)d_in[2];
    const float* bout = (const float*)d_in[3];
    float* out = (float*)d_out;

    float* acc_ws = (float*)d_ws;                 // [B,H] running sums
    float* F_ws   = acc_ws + (size_t)B_ * H_;     // [B,H] exp(log_f at s=S-1)

    hipMemsetAsync(d_ws, 0, 2 * (size_t)B_ * H_ * sizeof(float), stream);

    dim3 grid(S_ / TS, H_ / TH, B_);
    fused_gemm_reduce<<<grid, 256, 0, stream>>>(x, w_in, acc_ws, F_ws);
    out_gemv<<<O_ / 4, 256, 0, stream>>>(wout, bout, acc_ws, F_ws, out);
}

// Round 2
// 772.600 us; speedup vs baseline: 3.6731x; 3.6731x over previous
//
#include <hip/hip_runtime.h>
#include <math.h>

// Problem constants (fixed by setup_inputs)
constexpr int B_ = 4, S_ = 8192, D_ = 1024, H_ = 1024, O_ = 1024;

typedef __bf16 bf16x8 __attribute__((ext_vector_type(8)));
typedef float  f32x4  __attribute__((ext_vector_type(4)));

__device__ __forceinline__ float softplusf(float x) {
    if (x > 20.f) return x;
    if (x < -20.f) return expf(x);
    return log1pf(expf(x));
}

// ---------------------------------------------------------------------------
// fp32 -> bf16 conversion (8 elems/thread, 16B stores)
// ---------------------------------------------------------------------------
__global__ __launch_bounds__(256) void cvt_bf16(const float* __restrict__ src,
                                                __bf16* __restrict__ dst, int n8) {
    int i = blockIdx.x * blockDim.x + threadIdx.x;
    if (i >= n8) return;
    const float4* s = (const float4*)src + (size_t)i * 2;
    float4 a = s[0], b = s[1];
    bf16x8 v = {(__bf16)a.x, (__bf16)a.y, (__bf16)a.z, (__bf16)a.w,
                (__bf16)b.x, (__bf16)b.y, (__bf16)b.z, (__bf16)b.w};
    *((bf16x8*)dst + i) = v;
}

// ---------------------------------------------------------------------------
// bf16 MFMA GEMM (z = x @ w_in^T for 3 gates) fused with elementwise chain
// and s-reduction.  Math:
//   h_last[b,h] = exp(-sp(d_{S-1})) * (0.5 + sum_s exp(d_s + log_g(hg_s)))
//   d = sp(-f) - sp(-i);  log_g(x) = x>=0 ? log(x+0.5) : -sp(-x)
// Block tile: BM=128 (s) x BN=64 (h), BK=32. 4 waves, each 64s x 32h.
// ---------------------------------------------------------------------------
constexpr int BM = 128, BN = 64, BK = 32;

__global__ __launch_bounds__(256) void gemm_fused_bf16(
    const __bf16* __restrict__ xb, const __bf16* __restrict__ wb,
    float* __restrict__ acc_ws, float* __restrict__ F_ws)
{
    __shared__ __bf16 sA[BM * BK];      // 8 KB, 16B slots, XOR-swizzled
    __shared__ __bf16 sB[3 * BN * BK];  // 12 KB
    __shared__ float colsum[BN];

    const int b    = blockIdx.z;
    const int h0   = blockIdx.x * BN;
    const int s0   = blockIdx.y * BM;
    const int tid  = threadIdx.x;
    const int lane = tid & 63;
    const int wid  = tid >> 6;
    const int wm   = wid >> 1;  // 0..1 : s offset wm*64
    const int wn   = wid & 1;   // 0..1 : h offset wn*32
    const int lr   = lane & 15;
    const int quad = lane >> 4;

    if (tid < BN) colsum[tid] = 0.f;

    // --- staging setup: wave handles wave-loads u = wid*5 + j -------------
    // Each wave-load: 64 lanes x 16B -> 1KB = 16 rows of 32 bf16.
    // LDS dest is base + lane*16 (HW); we put global quad q = sp ^ ((row>>1)&3)
    // into slot sp so compute-side reads are 2-way-max bank aliased (free).
    const __bf16* gptr[5];
    __bf16* lptr[5];
    #pragma unroll
    for (int j = 0; j < 5; ++j) {
        int u  = wid * 5 + j;        // 0..19 : 0-7 = A chunks, 8-19 = B chunks
        int rl = lane >> 2;          // row within 16-row chunk
        int sp = lane & 3;           // slot position
        if (u < 8) {
            int row = u * 16 + rl;   // 0..127
            int q   = sp ^ ((row >> 1) & 3);
            gptr[j] = xb + ((size_t)(b * S_ + s0 + row)) * D_ + q * 8;
            lptr[j] = sA + u * 512;
        } else {
            int v   = u - 8;         // g = v>>2, chunk c = v&3
            int row = (v & 3) * 16 + rl;  // 0..63
            int q   = sp ^ ((row >> 1) & 3);
            gptr[j] = wb + (size_t)(v >> 2) * H_ * D_ + (size_t)(h0 + row) * D_ + q * 8;
            lptr[j] = sB + v * 512;
        }
    }

    // --- loop-invariant fragment pointers ---------------------------------
    const bf16x8* aptr[4];
    #pragma unroll
    for (int t = 0; t < 4; ++t) {
        int row  = wm * 64 + t * 16 + lr;
        int slot = quad ^ ((row >> 1) & 3);
        aptr[t] = (const bf16x8*)(sA + row * BK + slot * 8);
    }
    const bf16x8* bptr[3][2];
    #pragma unroll
    for (int g = 0; g < 3; ++g)
        #pragma unroll
        for (int n = 0; n < 2; ++n) {
            int row  = wn * 32 + n * 16 + lr;
            int slot = quad ^ ((row >> 1) & 3);
            bptr[g][n] = (const bf16x8*)(sB + g * (BN * BK) + row * BK + slot * 8);
        }

    f32x4 acc[3][4][2] = {};

    for (int k0 = 0; k0 < D_ / BK; ++k0) {
        #pragma unroll
        for (int j = 0; j < 5; ++j) {
            __builtin_amdgcn_global_load_lds(
                (const __attribute__((address_space(1))) void*)gptr[j],
                (__attribute__((address_space(3))) void*)lptr[j], 16, 0, 0);
            gptr[j] += BK;
        }
        __syncthreads();

        bf16x8 af[4];
        #pragma unroll
        for (int t = 0; t < 4; ++t) af[t] = *aptr[t];
        #pragma unroll
        for (int g = 0; g < 3; ++g)
            #pragma unroll
            for (int n = 0; n < 2; ++n) {
                bf16x8 bfrag = *bptr[g][n];
                #pragma unroll
                for (int t = 0; t < 4; ++t)
                    acc[g][t][n] = __builtin_amdgcn_mfma_f32_16x16x32_bf16(
                        af[t], bfrag, acc[g][t][n], 0, 0, 0);
            }
        __syncthreads();
    }

    // --- epilogue: elementwise chain + column (s) reduction ---------------
    // C/D layout: col = lane&15, row = quad*4 + reg  [m89-verified]
    const bool lastS = (s0 + BM == S_);
    float vsum[2] = {0.f, 0.f};
    #pragma unroll
    for (int n = 0; n < 2; ++n) {
        #pragma unroll
        for (int t = 0; t < 4; ++t) {
            f32x4 fv = acc[0][t][n], iv = acc[1][t][n], hv = acc[2][t][n];
            #pragma unroll
            for (int r = 0; r < 4; ++r) {
                float f = fv[r], i = iv[r], h = hv[r];
                float d  = softplusf(-f) - softplusf(-i);
                float lg = (h >= 0.f) ? logf(h + 0.5f) : -softplusf(-h);
                vsum[n] += expf(d + lg);
                if (lastS && wm == 1 && t == 3 && quad == 3 && r == 3) {
                    // this element is global row s = S-1
                    F_ws[(size_t)b * H_ + h0 + wn * 32 + n * 16 + lr] =
                        expf(-softplusf(d));
                }
            }
        }
    }
    #pragma unroll
    for (int n = 0; n < 2; ++n) {
        float v = vsum[n];
        v += __shfl_xor(v, 16, 64);
        v += __shfl_xor(v, 32, 64);
        if (quad == 0) atomicAdd(&colsum[wn * 32 + n * 16 + lr], v);
    }
    __syncthreads();
    if (tid < BN)
        atomicAdd(&acc_ws[(size_t)b * H_ + h0 + tid], colsum[tid]);
}

// ---------------------------------------------------------------------------
// fp32 fallback (round-1 kernel) -- used only if ws_size is too small
// ---------------------------------------------------------------------------
constexpr int TS = 64, TH = 64, TK = 16, LDP = 68;

__global__ __launch_bounds__(256) void fused_gemm_reduce(
    const float* __restrict__ x, const float* __restrict__ win,
    float* __restrict__ acc_ws, float* __restrict__ F_ws)
{
    __shared__ __align__(16) float As[TK][LDP];
    __shared__ __align__(16) float Wf[TK][LDP];
    __shared__ __align__(16) float Wi[TK][LDP];
    __shared__ __align__(16) float Wh[TK][LDP];
    __shared__ float colsum[TH];

    const int b  = blockIdx.z;
    const int s0 = blockIdx.x * TS;
    const int h0 = blockIdx.y * TH;
    const int tid = threadIdx.x;
    const int tx = tid & 15;
    const int ty = tid >> 4;

    float accf[4][4] = {};
    float acci[4][4] = {};
    float acch[4][4] = {};

    const int lrow = tid >> 2;
    const int lk4  = (tid & 3) << 2;

    const float* xp  = x   + ((size_t)b * S_ + (s0 + lrow)) * D_ + lk4;
    const float* wfp = win + (size_t)(h0 + lrow) * D_ + lk4;
    const float* wip = wfp + (size_t)H_ * D_;
    const float* whp = wip + (size_t)H_ * D_;

    for (int k0 = 0; k0 < D_; k0 += TK) {
        float4 va = *(const float4*)(xp  + k0);
        float4 vf = *(const float4*)(wfp + k0);
        float4 vi = *(const float4*)(wip + k0);
        float4 vh = *(const float4*)(whp + k0);
        __syncthreads();
        As[lk4+0][lrow]=va.x; As[lk4+1][lrow]=va.y; As[lk4+2][lrow]=va.z; As[lk4+3][lrow]=va.w;
        Wf[lk4+0][lrow]=vf.x; Wf[lk4+1][lrow]=vf.y; Wf[lk4+2][lrow]=vf.z; Wf[lk4+3][lrow]=vf.w;
        Wi[lk4+0][lrow]=vi.x; Wi[lk4+1][lrow]=vi.y; Wi[lk4+2][lrow]=vi.z; Wi[lk4+3][lrow]=vi.w;
        Wh[lk4+0][lrow]=vh.x; Wh[lk4+1][lrow]=vh.y; Wh[lk4+2][lrow]=vh.z; Wh[lk4+3][lrow]=vh.w;
        __syncthreads();
        #pragma unroll
        for (int k = 0; k < TK; ++k) {
            float4 a4 = *(const float4*)&As[k][ty << 2];
            float4 f4 = *(const float4*)&Wf[k][tx << 2];
            float4 i4 = *(const float4*)&Wi[k][tx << 2];
            float4 h4 = *(const float4*)&Wh[k][tx << 2];
            float a[4]  = {a4.x, a4.y, a4.z, a4.w};
            float wf[4] = {f4.x, f4.y, f4.z, f4.w};
            float wi[4] = {i4.x, i4.y, i4.z, i4.w};
            float wh[4] = {h4.x, h4.y, h4.z, h4.w};
            #pragma unroll
            for (int r = 0; r < 4; ++r)
                #pragma unroll
                for (int c = 0; c < 4; ++c) {
                    accf[r][c] = fmaf(a[r], wf[c], accf[r][c]);
                    acci[r][c] = fmaf(a[r], wi[c], acci[r][c]);
                    acch[r][c] = fmaf(a[r], wh[c], acch[r][c]);
                }
        }
    }

    const bool last_s = (s0 + TS == S_);
    float cval[4] = {0.f, 0.f, 0.f, 0.f};
    #pragma unroll
    for (int c = 0; c < 4; ++c)
        #pragma unroll
        for (int r = 0; r < 4; ++r) {
            float f = accf[r][c], i = acci[r][c], h = acch[r][c];
            float d  = softplusf(-f) - softplusf(-i);
            float lg = (h >= 0.f) ? logf(h + 0.5f) : -softplusf(-h);
            cval[c] += expf(d + lg);
            if (last_s && ty == 15 && r == 3)
                F_ws[(size_t)b * H_ + h0 + (tx << 2) + c] = expf(-softplusf(d));
        }
    if (tid < TH) colsum[tid] = 0.f;
    __syncthreads();
    #pragma unroll
    for (int c = 0; c < 4; ++c)
        atomicAdd(&colsum[(tx << 2) + c], cval[c]);
    __syncthreads();
    if (tid < TH)
        atomicAdd(&acc_ws[(size_t)b * H_ + h0 + tid], colsum[tid]);
}

// out[b,o] = b_out[o] + sum_h w_out[o,h] * F[b,h]*(0.5 + acc[b,h])
__global__ __launch_bounds__(256) void out_gemv(
    const float* __restrict__ wout, const float* __restrict__ bout,
    const float* __restrict__ acc_ws, const float* __restrict__ F_ws,
    float* __restrict__ out)
{
    const int lane = threadIdx.x & 63;
    const int o = blockIdx.x * 4 + (threadIdx.x >> 6);
    float s[B_] = {};
    for (int h = lane; h < H_; h += 64) {
        float w = wout[(size_t)o * H_ + h];
        #pragma unroll
        for (int b = 0; b < B_; ++b) {
            float hv = F_ws[b * H_ + h] * (0.5f + acc_ws[b * H_ + h]);
            s[b] = fmaf(w, hv, s[b]);
        }
    }
    #pragma unroll
    for (int b = 0; b < B_; ++b)
        #pragma unroll
        for (int off = 32; off > 0; off >>= 1)
            s[b] += __shfl_down(s[b], off, 64);
    if (lane == 0) {
        float bo = bout[o];
        #pragma unroll
        for (int b = 0; b < B_; ++b)
            out[(size_t)b * O_ + o] = s[b] + bo;
    }
}

extern "C" void kernel_launch(void* const* d_in, const int* in_sizes, int n_in,
                              void* d_out, int out_size, void* d_ws, size_t ws_size,
                              hipStream_t stream) {
    const float* x    = (const float*)d_in[0];
    const float* w_in = (const float*)d_in[1];
    const float* wout = (const float*)d_in[2];
    const float* bout = (const float*)d_in[3];
    float* out = (float*)d_out;

    float* acc_ws = (float*)d_ws;                 // [B,H] running sums
    float* F_ws   = acc_ws + (size_t)B_ * H_;     // [B,H] exp(log_f at s=S-1)

    hipMemsetAsync(d_ws, 0, 2 * (size_t)B_ * H_ * sizeof(float), stream);

    const size_t nx = (size_t)B_ * S_ * D_;       // 33.5M
    const size_t nw = (size_t)3 * H_ * D_;        // 3.1M
    const size_t bf_off = 32768;                  // past acc/F, 16B aligned
    const size_t need = bf_off + (nx + nw) * sizeof(__bf16);

    if (ws_size >= need) {
        __bf16* xb = (__bf16*)((char*)d_ws + bf_off);
        __bf16* wb = xb + nx;
        cvt_bf16<<<(int)(nx / 8 / 256), 256, 0, stream>>>(x, xb, (int)(nx / 8));
        cvt_bf16<<<(int)(nw / 8 / 256), 256, 0, stream>>>(w_in, wb, (int)(nw / 8));
        dim3 grid(H_ / BN, S_ / BM, B_);
        gemm_fused_bf16<<<grid, 256, 0, stream>>>(xb, wb, acc_ws, F_ws);
    } else {
        dim3 grid(S_ / TS, H_ / TH, B_);
        fused_gemm_reduce<<<grid, 256, 0, stream>>>(x, w_in, acc_ws, F_ws);
    }
    out_gemv<<<O_ / 4, 256, 0, stream>>>(wout, bout, acc_ws, F_ws, out);
}

// Round 3
// 469.593 us; speedup vs baseline: 6.0431x; 1.6453x over previous
//
#include <hip/hip_runtime.h>
#include <math.h>

// Problem constants (fixed by setup_inputs)
constexpr int B_ = 4, S_ = 8192, D_ = 1024, H_ = 1024, O_ = 1024;

typedef __bf16 bf16x8 __attribute__((ext_vector_type(8)));
typedef float  f32x4  __attribute__((ext_vector_type(4)));

__device__ __forceinline__ float softplusf(float x) {
    if (x > 20.f) return x;
    if (x < -20.f) return expf(x);
    return log1pf(expf(x));
}

// ---------------------------------------------------------------------------
// fp32 -> bf16 conversion (8 elems/thread, 16B stores)
// ---------------------------------------------------------------------------
__global__ __launch_bounds__(256) void cvt_bf16(const float* __restrict__ src,
                                                __bf16* __restrict__ dst, int n8) {
    int i = blockIdx.x * blockDim.x + threadIdx.x;
    if (i >= n8) return;
    const float4* s = (const float4*)src + (size_t)i * 2;
    float4 a = s[0], b = s[1];
    bf16x8 v = {(__bf16)a.x, (__bf16)a.y, (__bf16)a.z, (__bf16)a.w,
                (__bf16)b.x, (__bf16)b.y, (__bf16)b.z, (__bf16)b.w};
    *((bf16x8*)dst + i) = v;
}

// ---------------------------------------------------------------------------
// bf16 MFMA GEMM (z = x @ w_in^T for 3 gates) fused with elementwise chain
// and s-reduction, double-buffered LDS, exp-form epilogue.
//   h_last[b,h] = F * (0.5 + sum_s term_s)
//   term = (1+e^{-f})/(1+e^{-i}) * g(h);  g(h)= h>=0 ? h+0.5 : e^h/(1+e^h)
//   F (at s=S-1) = (1+e^{-i}) / ((1+e^{-f}) + (1+e^{-i}))
// Block tile: BM=128 (s) x BN=64 (h), BK=32. 4 waves, each 64s x 32h.
// ---------------------------------------------------------------------------
constexpr int BM = 128, BN = 64, BK = 32;
constexpr int BUF_ELEMS = (BM + 3 * BN) * BK;  // 10240 bf16 = 20 KB

__global__ __launch_bounds__(256) void gemm_fused_bf16(
    const __bf16* __restrict__ xb, const __bf16* __restrict__ wb,
    float* __restrict__ acc_ws, float* __restrict__ F_ws)
{
    __shared__ __bf16 sbuf[2][BUF_ELEMS];   // 40 KB double buffer
    __shared__ float colsum[BN];

    const int b    = blockIdx.z;
    const int h0   = blockIdx.x * BN;
    const int s0   = blockIdx.y * BM;
    const int tid  = threadIdx.x;
    const int lane = tid & 63;
    const int wid  = tid >> 6;
    const int wm   = wid >> 1;  // 0..1 : s offset wm*64
    const int wn   = wid & 1;   // 0..1 : h offset wn*32
    const int lr   = lane & 15;
    const int quad = lane >> 4;

    if (tid < BN) colsum[tid] = 0.f;

    // --- staging setup: wave handles wave-loads u = wid*5 + j -------------
    // Each wave-load: 64 lanes x 16B -> 1KB = 16 rows of 32 bf16.
    // LDS dest is wave-uniform base + lane*16 (HW). Global quad
    // q = sp ^ ((row>>1)&3) goes into slot sp -> compute-side reads are
    // 2-way-max bank aliased (free).
    const __bf16* gptr[5];
    __bf16* lptr0[5];
    __bf16* lptr1[5];
    #pragma unroll
    for (int j = 0; j < 5; ++j) {
        int u  = wid * 5 + j;        // 0..19 : 0-7 = A chunks, 8-19 = B chunks
        int rl = lane >> 2;          // row within 16-row chunk
        int sp = lane & 3;           // slot position
        int off;
        if (u < 8) {
            int row = u * 16 + rl;   // 0..127
            int q   = sp ^ ((row >> 1) & 3);
            gptr[j] = xb + ((size_t)(b * S_ + s0 + row)) * D_ + q * 8;
            off = u * 512;
        } else {
            int v   = u - 8;         // g = v>>2, chunk c = v&3
            int row = (v & 3) * 16 + rl;  // 0..63
            int q   = sp ^ ((row >> 1) & 3);
            gptr[j] = wb + (size_t)(v >> 2) * H_ * D_ + (size_t)(h0 + row) * D_ + q * 8;
            off = BM * BK + v * 512;
        }
        lptr0[j] = &sbuf[0][off];
        lptr1[j] = &sbuf[1][off];
    }

    // --- loop-invariant fragment element-offsets ---------------------------
    int aofs[4];
    #pragma unroll
    for (int t = 0; t < 4; ++t) {
        int row  = wm * 64 + t * 16 + lr;
        int slot = quad ^ ((row >> 1) & 3);
        aofs[t] = row * BK + slot * 8;
    }
    int bofs[3][2];
    #pragma unroll
    for (int g = 0; g < 3; ++g)
        #pragma unroll
        for (int n = 0; n < 2; ++n) {
            int row  = wn * 32 + n * 16 + lr;
            int slot = quad ^ ((row >> 1) & 3);
            bofs[g][n] = BM * BK + g * (BN * BK) + row * BK + slot * 8;
        }

    f32x4 acc[3][4][2] = {};

    auto issue_loads = [&](int nxt) {
        #pragma unroll
        for (int j = 0; j < 5; ++j) {
            __builtin_amdgcn_global_load_lds(
                (const __attribute__((address_space(1))) void*)gptr[j],
                (__attribute__((address_space(3))) void*)(nxt ? lptr1[j] : lptr0[j]),
                16, 0, 0);
            gptr[j] += BK;
        }
    };
    auto compute = [&](const __bf16* base) {
        bf16x8 af[4];
        #pragma unroll
        for (int t = 0; t < 4; ++t) af[t] = *(const bf16x8*)(base + aofs[t]);
        #pragma unroll
        for (int g = 0; g < 3; ++g)
            #pragma unroll
            for (int n = 0; n < 2; ++n) {
                bf16x8 bfrag = *(const bf16x8*)(base + bofs[g][n]);
                #pragma unroll
                for (int t = 0; t < 4; ++t)
                    acc[g][t][n] = __builtin_amdgcn_mfma_f32_16x16x32_bf16(
                        af[t], bfrag, acc[g][t][n], 0, 0, 0);
            }
    };

    issue_loads(0);  // k-chunk 0 -> buf0
    for (int k0 = 0; k0 < D_ / BK; k0 += 2) {
        // barrier AFTER compute(prev) and BEFORE touching next buffer:
        // its implicit vmcnt(0) drains loads issued one full compute ago.
        __syncthreads();
        issue_loads(1);               // k-chunk k0+1 -> buf1 (overlaps compute)
        compute(&sbuf[0][0]);
        __syncthreads();
        if (k0 + 2 < D_ / BK) issue_loads(0);  // k-chunk k0+2 -> buf0
        compute(&sbuf[1][0]);
    }

    // --- epilogue: exp-form elementwise chain + column (s) reduction ------
    // C/D layout: col = lane&15, row = quad*4 + reg  [m89-verified]
    const bool lastS = (s0 + BM == S_);
    float vsum[2] = {0.f, 0.f};
    #pragma unroll
    for (int n = 0; n < 2; ++n) {
        #pragma unroll
        for (int t = 0; t < 4; ++t) {
            f32x4 fv = acc[0][t][n], iv = acc[1][t][n], hv = acc[2][t][n];
            #pragma unroll
            for (int r = 0; r < 4; ++r) {
                float ef = __expf(-fv[r]);
                float ei = __expf(-iv[r]);
                float af1 = 1.f + ef, ai1 = 1.f + ei;
                float h  = hv[r];
                float eh = __expf(h);
                float g  = (h >= 0.f) ? (h + 0.5f)
                                      : (eh * __builtin_amdgcn_rcpf(1.f + eh));
                vsum[n] += af1 * __builtin_amdgcn_rcpf(ai1) * g;
                if (lastS && wm == 1 && t == 3 && quad == 3 && r == 3) {
                    // this element is global row s = S-1
                    F_ws[(size_t)b * H_ + h0 + wn * 32 + n * 16 + lr] =
                        ai1 * __builtin_amdgcn_rcpf(af1 + ai1);
                }
            }
        }
    }
    #pragma unroll
    for (int n = 0; n < 2; ++n) {
        float v = vsum[n];
        v += __shfl_xor(v, 16, 64);
        v += __shfl_xor(v, 32, 64);
        if (quad == 0) atomicAdd(&colsum[wn * 32 + n * 16 + lr], v);
    }
    __syncthreads();
    if (tid < BN)
        atomicAdd(&acc_ws[(size_t)b * H_ + h0 + tid], colsum[tid]);
}

// ---------------------------------------------------------------------------
// fp32 fallback (round-1 kernel) -- used only if ws_size is too small
// ---------------------------------------------------------------------------
constexpr int TS = 64, TH = 64, TK = 16, LDP = 68;

__global__ __launch_bounds__(256) void fused_gemm_reduce(
    const float* __restrict__ x, const float* __restrict__ win,
    float* __restrict__ acc_ws, float* __restrict__ F_ws)
{
    __shared__ __align__(16) float As[TK][LDP];
    __shared__ __align__(16) float Wf[TK][LDP];
    __shared__ __align__(16) float Wi[TK][LDP];
    __shared__ __align__(16) float Wh[TK][LDP];
    __shared__ float colsum[TH];

    const int b  = blockIdx.z;
    const int s0 = blockIdx.x * TS;
    const int h0 = blockIdx.y * TH;
    const int tid = threadIdx.x;
    const int tx = tid & 15;
    const int ty = tid >> 4;

    float accf[4][4] = {};
    float acci[4][4] = {};
    float acch[4][4] = {};

    const int lrow = tid >> 2;
    const int lk4  = (tid & 3) << 2;

    const float* xp  = x   + ((size_t)b * S_ + (s0 + lrow)) * D_ + lk4;
    const float* wfp = win + (size_t)(h0 + lrow) * D_ + lk4;
    const float* wip = wfp + (size_t)H_ * D_;
    const float* whp = wip + (size_t)H_ * D_;

    for (int k0 = 0; k0 < D_; k0 += TK) {
        float4 va = *(const float4*)(xp  + k0);
        float4 vf = *(const float4*)(wfp + k0);
        float4 vi = *(const float4*)(wip + k0);
        float4 vh = *(const float4*)(whp + k0);
        __syncthreads();
        As[lk4+0][lrow]=va.x; As[lk4+1][lrow]=va.y; As[lk4+2][lrow]=va.z; As[lk4+3][lrow]=va.w;
        Wf[lk4+0][lrow]=vf.x; Wf[lk4+1][lrow]=vf.y; Wf[lk4+2][lrow]=vf.z; Wf[lk4+3][lrow]=vf.w;
        Wi[lk4+0][lrow]=vi.x; Wi[lk4+1][lrow]=vi.y; Wi[lk4+2][lrow]=vi.z; Wi[lk4+3][lrow]=vi.w;
        Wh[lk4+0][lrow]=vh.x; Wh[lk4+1][lrow]=vh.y; Wh[lk4+2][lrow]=vh.z; Wh[lk4+3][lrow]=vh.w;
        __syncthreads();
        #pragma unroll
        for (int k = 0; k < TK; ++k) {
            float4 a4 = *(const float4*)&As[k][ty << 2];
            float4 f4 = *(const float4*)&Wf[k][tx << 2];
            float4 i4 = *(const float4*)&Wi[k][tx << 2];
            float4 h4 = *(const float4*)&Wh[k][tx << 2];
            float a[4]  = {a4.x, a4.y, a4.z, a4.w};
            float wf[4] = {f4.x, f4.y, f4.z, f4.w};
            float wi[4] = {i4.x, i4.y, i4.z, i4.w};
            float wh[4] = {h4.x, h4.y, h4.z, h4.w};
            #pragma unroll
            for (int r = 0; r < 4; ++r)
                #pragma unroll
                for (int c = 0; c < 4; ++c) {
                    accf[r][c] = fmaf(a[r], wf[c], accf[r][c]);
                    acci[r][c] = fmaf(a[r], wi[c], acci[r][c]);
                    acch[r][c] = fmaf(a[r], wh[c], acch[r][c]);
                }
        }
    }

    const bool last_s = (s0 + TS == S_);
    float cval[4] = {0.f, 0.f, 0.f, 0.f};
    #pragma unroll
    for (int c = 0; c < 4; ++c)
        #pragma unroll
        for (int r = 0; r < 4; ++r) {
            float f = accf[r][c], i = acci[r][c], h = acch[r][c];
            float d  = softplusf(-f) - softplusf(-i);
            float lg = (h >= 0.f) ? logf(h + 0.5f) : -softplusf(-h);
            cval[c] += expf(d + lg);
            if (last_s && ty == 15 && r == 3)
                F_ws[(size_t)b * H_ + h0 + (tx << 2) + c] = expf(-softplusf(d));
        }
    if (tid < TH) colsum[tid] = 0.f;
    __syncthreads();
    #pragma unroll
    for (int c = 0; c < 4; ++c)
        atomicAdd(&colsum[(tx << 2) + c], cval[c]);
    __syncthreads();
    if (tid < TH)
        atomicAdd(&acc_ws[(size_t)b * H_ + h0 + tid], colsum[tid]);
}

// out[b,o] = b_out[o] + sum_h w_out[o,h] * F[b,h]*(0.5 + acc[b,h])
__global__ __launch_bounds__(256) void out_gemv(
    const float* __restrict__ wout, const float* __restrict__ bout,
    const float* __restrict__ acc_ws, const float* __restrict__ F_ws,
    float* __restrict__ out)
{
    const int lane = threadIdx.x & 63;
    const int o = blockIdx.x * 4 + (threadIdx.x >> 6);
    float s[B_] = {};
    for (int h = lane; h < H_; h += 64) {
        float w = wout[(size_t)o * H_ + h];
        #pragma unroll
        for (int b = 0; b < B_; ++b) {
            float hv = F_ws[b * H_ + h] * (0.5f + acc_ws[b * H_ + h]);
            s[b] = fmaf(w, hv, s[b]);
        }
    }
    #pragma unroll
    for (int b = 0; b < B_; ++b)
        #pragma unroll
        for (int off = 32; off > 0; off >>= 1)
            s[b] += __shfl_down(s[b], off, 64);
    if (lane == 0) {
        float bo = bout[o];
        #pragma unroll
        for (int b = 0; b < B_; ++b)
            out[(size_t)b * O_ + o] = s[b] + bo;
    }
}

extern "C" void kernel_launch(void* const* d_in, const int* in_sizes, int n_in,
                              void* d_out, int out_size, void* d_ws, size_t ws_size,
                              hipStream_t stream) {
    const float* x    = (const float*)d_in[0];
    const float* w_in = (const float*)d_in[1];
    const float* wout = (const float*)d_in[2];
    const float* bout = (const float*)d_in[3];
    float* out = (float*)d_out;

    float* acc_ws = (float*)d_ws;                 // [B,H] running sums
    float* F_ws   = acc_ws + (size_t)B_ * H_;     // [B,H] exp(log_f at s=S-1)

    hipMemsetAsync(d_ws, 0, 2 * (size_t)B_ * H_ * sizeof(float), stream);

    const size_t nx = (size_t)B_ * S_ * D_;       // 33.5M
    const size_t nw = (size_t)3 * H_ * D_;        // 3.1M
    const size_t bf_off = 32768;                  // past acc/F, 16B aligned
    const size_t need = bf_off + (nx + nw) * sizeof(__bf16);

    if (ws_size >= need) {
        __bf16* xb = (__bf16*)((char*)d_ws + bf_off);
        __bf16* wb = xb + nx;
        cvt_bf16<<<(int)(nx / 8 / 256), 256, 0, stream>>>(x, xb, (int)(nx / 8));
        cvt_bf16<<<(int)(nw / 8 / 256), 256, 0, stream>>>(w_in, wb, (int)(nw / 8));
        dim3 grid(H_ / BN, S_ / BM, B_);
        gemm_fused_bf16<<<grid, 256, 0, stream>>>(xb, wb, acc_ws, F_ws);
    } else {
        dim3 grid(S_ / TS, H_ / TH, B_);
        fused_gemm_reduce<<<grid, 256, 0, stream>>>(x, w_in, acc_ws, F_ws);
    }
    out_gemv<<<O_ / 4, 256, 0, stream>>>(wout, bout, acc_ws, F_ws, out);
}